// Round 1
// baseline (1751.200 us; speedup 1.0000x reference)
//
#include <hip/hip_runtime.h>

#define K_CODES 1024
#define D_DIM 128
#define N_ROWS 65536
#define DECAY_F 0.99f
#define OMD_F 0.01f
#define EPS_F 1e-5f
#define CHUNK 16

// ---------------------------------------------------------------------------
// ws layout (floats):
//   [0, K)            batch_cluster  (zeroed per call)
//   [K, K+K*D)        batch_ema      (zeroed per call)
//   [K+K*D]           loss accum     (zeroed per call)
//   [K+K*D+1, +K)     e_norm
//   [K+K*D+1+K, +K)   smoothed
// ---------------------------------------------------------------------------

__global__ void vq_enorm(const float* __restrict__ emb, float* __restrict__ enorm) {
    int k = blockIdx.x * blockDim.x + threadIdx.x;
    if (k >= K_CODES) return;
    const float4* e4 = (const float4*)(emb + (size_t)k * D_DIM);
    float s = 0.f;
#pragma unroll
    for (int i = 0; i < D_DIM / 4; ++i) {
        float4 v = e4[i];
        s += v.x * v.x + v.y * v.y + v.z * v.z + v.w * v.w;
    }
    enorm[k] = s;
}

// Main kernel: 2 threads per row; each thread owns a 64-dim half-row in regs.
// Block = 256 threads => 128 rows/block; grid = 512 blocks.
__global__ __launch_bounds__(256) void vq_main(
    const float* __restrict__ z, const float* __restrict__ emb,
    const float* __restrict__ enorm,
    float* __restrict__ out_zq, float* __restrict__ out_idx,
    float* __restrict__ bc, float* __restrict__ be, float* __restrict__ loss_acc)
{
    __shared__ float4 eb[CHUNK][D_DIM / 4];   // 16 codes x 128 floats = 8 KB
    __shared__ float  en[CHUNK];

    const int tid  = threadIdx.x;
    const int half = tid & 1;                  // which 64-dim half of the row
    const int row  = blockIdx.x * 128 + (tid >> 1);

    // Load my half-row into registers (16 float4 = 64 floats)
    float4 zr[16];
    const float4* zp = (const float4*)(z + (size_t)row * D_DIM + half * 64);
#pragma unroll
    for (int i = 0; i < 16; ++i) zr[i] = zp[i];

    float best  = 3.4e38f;
    int   besti = 0;

    for (int c = 0; c < K_CODES / CHUNK; ++c) {
        __syncthreads();
        // Stage 16 codes (512 float4) with 256 threads: 2 float4 each, coalesced
        const float4* ep = (const float4*)emb + (size_t)c * CHUNK * (D_DIM / 4);
        ((float4*)eb)[tid]       = ep[tid];
        ((float4*)eb)[tid + 256] = ep[tid + 256];
        if (tid < CHUNK) en[tid] = enorm[c * CHUNK + tid];
        __syncthreads();

        for (int j = 0; j < CHUNK; ++j) {
            float4 acc = {0.f, 0.f, 0.f, 0.f};
#pragma unroll
            for (int i = 0; i < 16; ++i) {
                float4 e = eb[j][half * 16 + i];   // broadcast (2 addrs/wave: free)
                acc.x += zr[i].x * e.x;
                acc.y += zr[i].y * e.y;
                acc.z += zr[i].z * e.z;
                acc.w += zr[i].w * e.w;
            }
            float part = (acc.x + acc.y) + (acc.z + acc.w);
            float dot  = part + __shfl_xor(part, 1, 64);  // commutative: both lanes identical
            float score = en[j] - 2.0f * dot;
            int   code  = c * CHUNK + j;
            if (score < best) { best = score; besti = code; }
        }
    }

    // ---------------- epilogue ----------------
    if (half == 0) {
        out_idx[row] = (float)besti;
        atomicAdd(bc + besti, 1.0f);
    }

    const float4* eq = (const float4*)(emb + (size_t)besti * D_DIM + half * 64);
    float4* oz = (float4*)(out_zq + (size_t)row * D_DIM + half * 64);
    float*  bep = be + (size_t)besti * D_DIM + half * 64;

    float ls = 0.f;
#pragma unroll
    for (int i = 0; i < 16; ++i) {
        float4 q  = eq[i];
        float4 zv = zr[i];
        float4 df = {q.x - zv.x, q.y - zv.y, q.z - zv.z, q.w - zv.w};
        ls += df.x * df.x + df.y * df.y + df.z * df.z + df.w * df.w;
        // z_q_st = z + (z_q - z), reference op order
        float4 o = {zv.x + df.x, zv.y + df.y, zv.z + df.z, zv.w + df.w};
        oz[i] = o;
        atomicAdd(bep + 4 * i + 0, zv.x);
        atomicAdd(bep + 4 * i + 1, zv.y);
        atomicAdd(bep + 4 * i + 2, zv.z);
        atomicAdd(bep + 4 * i + 3, zv.w);
    }

    // loss: wave reduce then one atomic per wave
#pragma unroll
    for (int off = 32; off > 0; off >>= 1) ls += __shfl_down(ls, off, 64);
    if ((tid & 63) == 0) atomicAdd(loss_acc, ls);
}

__global__ void vq_finalize1(const float* __restrict__ cs, const float* __restrict__ bc,
                             const float* __restrict__ loss_acc,
                             float* __restrict__ out_ncs, float* __restrict__ out_loss,
                             float* __restrict__ smoothed)
{
    __shared__ float red[K_CODES];
    int k = threadIdx.x;   // 1024 threads
    float ncs = cs[k] * DECAY_F + OMD_F * bc[k];
    out_ncs[k] = ncs;
    red[k] = ncs;
    __syncthreads();
    for (int s = 512; s > 0; s >>= 1) {
        if (k < s) red[k] += red[k + s];
        __syncthreads();
    }
    float n = red[0];
    smoothed[k] = (ncs + EPS_F) / (n + (float)K_CODES * EPS_F) * n;
    if (k == 0) out_loss[0] = loss_acc[0] / (float)((size_t)N_ROWS * D_DIM);
}

__global__ void vq_finalize2(const float* __restrict__ ema_w, const float* __restrict__ be,
                             const float* __restrict__ smoothed,
                             float* __restrict__ out_emb, float* __restrict__ out_ema)
{
    int i = blockIdx.x * blockDim.x + threadIdx.x;   // K*D
    float e = ema_w[i] * DECAY_F + OMD_F * be[i];
    out_ema[i] = e;
    out_emb[i] = e / smoothed[i >> 7];
}

extern "C" void kernel_launch(void* const* d_in, const int* in_sizes, int n_in,
                              void* d_out, int out_size, void* d_ws, size_t ws_size,
                              hipStream_t stream) {
    const float* z    = (const float*)d_in[0];   // [16,4096,128]
    const float* emb  = (const float*)d_in[1];   // [1024,128]
    const float* cs   = (const float*)d_in[2];   // [1024]
    const float* ema  = (const float*)d_in[3];   // [1024,128]

    float* out    = (float*)d_out;
    float* o_zq   = out;                         // 8388608
    float* o_idx  = o_zq + (size_t)N_ROWS * D_DIM;   // 65536
    float* o_loss = o_idx + N_ROWS;                  // 1
    float* o_emb  = o_loss + 1;                      // 131072
    float* o_ncs  = o_emb + K_CODES * D_DIM;         // 1024
    float* o_ema  = o_ncs + K_CODES;                 // 131072

    float* ws       = (float*)d_ws;
    float* bc       = ws;
    float* be       = ws + K_CODES;
    float* lacc     = be + (size_t)K_CODES * D_DIM;
    float* enorm    = lacc + 1;
    float* smoothed = enorm + K_CODES;

    hipMemsetAsync(d_ws, 0, (size_t)(K_CODES + K_CODES * D_DIM + 1) * sizeof(float), stream);
    vq_enorm<<<4, 256, 0, stream>>>(emb, enorm);
    vq_main<<<N_ROWS / 128, 256, 0, stream>>>(z, emb, enorm, o_zq, o_idx, bc, be, lacc);
    vq_finalize1<<<1, K_CODES, 0, stream>>>(cs, bc, lacc, o_ncs, o_loss, smoothed);
    vq_finalize2<<<K_CODES * D_DIM / 256, 256, 0, stream>>>(ema, be, smoothed, o_emb, o_ema);
}

// Round 2
// 1392.541 us; speedup vs baseline: 1.2576x; 1.2576x over previous
//
#include <hip/hip_runtime.h>

#define K_CODES 1024
#define D_DIM 128
#define N_ROWS 65536
#define DECAY_F 0.99f
#define OMD_F 0.01f
#define EPS_F 1e-5f

// Padded row for bf16 E images: 128 -> 136 elements (272 B) => bank spread
#define EPAD 136
#define CHUNK_CODES 128
#define N_CHUNKS (K_CODES / CHUNK_CODES)
#define CHUNK_USHORT (2 * CHUNK_CODES * EPAD)   // hi+lo image per chunk = 34816

// ---------------------------------------------------------------------------
// ws layout (float units):
//   WS_BC     bc[1024]          (zeroed per call)
//   WS_BE     be[131072]        (zeroed per call)
//   WS_LOSS   loss[1]           (zeroed per call)
//   WS_ENORM  enorm[1024]       fp32 ||e||^2
//   WS_SMOOTH smoothed[1024]
//   WS_I12    i12[2*65536] u32  top-2 candidate indices per row
//   WS_EIMG   e_img ushort[8 chunks][2 splits][128 codes][136]  bf16 bits
// ---------------------------------------------------------------------------
#define WS_BC     0
#define WS_BE     1024
#define WS_LOSS   132096
#define WS_ENORM  132112
#define WS_SMOOTH 133136
#define WS_I12    134160
#define WS_EIMG   265232

typedef __bf16 bf8_t __attribute__((ext_vector_type(8)));
typedef float  f4_t  __attribute__((ext_vector_type(4)));

__device__ inline unsigned short f2bf_bits(float f) {
    __bf16 h = (__bf16)f;
    return __builtin_bit_cast(unsigned short, h);
}
__device__ inline float bf_bits2f(unsigned short u) {
    __bf16 h = __builtin_bit_cast(__bf16, u);
    return (float)h;
}

// ---------------------------------------------------------------------------
__global__ void vq_enorm(const float* __restrict__ emb, float* __restrict__ enorm) {
    int k = blockIdx.x * blockDim.x + threadIdx.x;
    if (k >= K_CODES) return;
    const float4* e4 = (const float4*)(emb + (size_t)k * D_DIM);
    float s = 0.f;
#pragma unroll
    for (int i = 0; i < D_DIM / 4; ++i) {
        float4 v = e4[i];
        s += v.x * v.x + v.y * v.y + v.z * v.z + v.w * v.w;
    }
    enorm[k] = s;
}

// Split E into bf16 hi/lo padded images: e_img[chunk][split][c][136]
__global__ void vq_esplit(const float* __restrict__ emb, unsigned short* __restrict__ eimg) {
    int t = blockIdx.x * blockDim.x + threadIdx.x;   // 32768 = 1024 codes * 32 quads
    int code = t >> 5;
    int q = t & 31;
    float4 v = ((const float4*)(emb + (size_t)code * D_DIM))[q];
    int chunk = code >> 7, c = code & 127;
    size_t hbase = (size_t)chunk * CHUNK_USHORT + (size_t)c * EPAD + q * 4;
    size_t lbase = hbase + (size_t)CHUNK_CODES * EPAD;
    float vv[4] = {v.x, v.y, v.z, v.w};
    ushort4 hi, lo;
    unsigned short* hp = (unsigned short*)&hi;
    unsigned short* lp = (unsigned short*)&lo;
#pragma unroll
    for (int i = 0; i < 4; ++i) {
        unsigned short hb = f2bf_bits(vv[i]);
        hp[i] = hb;
        lp[i] = f2bf_bits(vv[i] - bf_bits2f(hb));
    }
    *(ushort4*)(eimg + hbase) = hi;
    *(ushort4*)(eimg + lbase) = lo;
}

// ---------------------------------------------------------------------------
// Scoring kernel: per-row top-2 candidate codes via split-bf16 MFMA.
// Block: 256 thr = 4 waves x 32 rows. Grid: 512 blocks (128 rows each).
// ---------------------------------------------------------------------------
__device__ inline void top2_update(float s, int code, float& s1, int& i1, float& s2, int& i2) {
    bool b1 = s < s1;
    bool b2 = s < s2;
    s2 = b1 ? s1 : (b2 ? s : s2);
    i2 = b1 ? i1 : (b2 ? code : i2);
    s1 = b1 ? s : s1;
    i1 = b1 ? code : i1;
}

__device__ inline void top2_merge(float& s1, int& i1, float& s2, int& i2,
                                  float t1, int j1, float t2, int j2) {
    bool bf = (t1 < s1) || (t1 == s1 && j1 < i1);
    float ns1 = bf ? t1 : s1;  int ni1 = bf ? j1 : i1;
    float ca  = bf ? s1 : t1;  int ia  = bf ? i1 : j1;
    float cb  = bf ? t2 : s2;  int ib  = bf ? j2 : i2;
    bool bs = (ca < cb) || (ca == cb && ia < ib);
    s1 = ns1; i1 = ni1;
    s2 = bs ? ca : cb; i2 = bs ? ia : ib;
}

__global__ __launch_bounds__(256, 2) void vq_score(
    const float* __restrict__ z, const unsigned short* __restrict__ eimg,
    const float* __restrict__ enorm, unsigned int* __restrict__ i12)
{
    __shared__ __align__(16) unsigned short lds[CHUNK_USHORT];  // 69632 B
    __shared__ float lds_en[CHUNK_CODES];

    const int tid  = threadIdx.x;
    const int wv   = tid >> 6;
    const int lane = tid & 63;
    const int l16  = lane & 15;
    const int quad = lane >> 4;

    // Resident z fragments: rows = block*128 + wv*32 + nt*16 + l16
    bf8_t zh[2][4], zl[2][4];
#pragma unroll
    for (int nt = 0; nt < 2; ++nt) {
        int row = blockIdx.x * 128 + wv * 32 + nt * 16 + l16;
        const float* zr = z + (size_t)row * D_DIM;
#pragma unroll
        for (int ks = 0; ks < 4; ++ks) {
            const float4* p = (const float4*)(zr + ks * 32 + quad * 8);
            float4 a = p[0], b = p[1];
            float v[8] = {a.x, a.y, a.z, a.w, b.x, b.y, b.z, b.w};
#pragma unroll
            for (int i = 0; i < 8; ++i) {
                __bf16 hh = (__bf16)v[i];
                zh[nt][ks][i] = hh;
                zl[nt][ks][i] = (__bf16)(v[i] - (float)hh);
            }
        }
    }

    float s1[2] = {3.4e38f, 3.4e38f}, s2[2] = {3.4e38f, 3.4e38f};
    int   i1[2] = {0, 0},             i2[2] = {0, 0};

    for (int chunk = 0; chunk < N_CHUNKS; ++chunk) {
        __syncthreads();
        // Stage chunk image (hi+lo, padded) + enorm slice
        {
            const uint4* src = (const uint4*)(eimg + (size_t)chunk * CHUNK_USHORT);
            uint4* dst = (uint4*)lds;
#pragma unroll
            for (int i = 0; i < 17; ++i) dst[tid + 256 * i] = src[tid + 256 * i];
            if (tid < CHUNK_CODES) lds_en[tid] = enorm[chunk * CHUNK_CODES + tid];
        }
        __syncthreads();

#pragma unroll
        for (int cg = 0; cg < 2; ++cg) {
            f4_t acc[4][2];
#pragma unroll
            for (int ct = 0; ct < 4; ++ct)
#pragma unroll
                for (int nt = 0; nt < 2; ++nt) acc[ct][nt] = (f4_t)(0.f);

#pragma unroll
            for (int ks = 0; ks < 4; ++ks) {
                bf8_t ah[4], al[4];
#pragma unroll
                for (int ct = 0; ct < 4; ++ct) {
                    int cl = cg * 64 + ct * 16 + l16;
                    int base = cl * EPAD + ks * 32 + quad * 8;
                    ah[ct] = *(const bf8_t*)&lds[base];
                    al[ct] = *(const bf8_t*)&lds[CHUNK_CODES * EPAD + base];
                }
#pragma unroll
                for (int ct = 0; ct < 4; ++ct)
#pragma unroll
                    for (int nt = 0; nt < 2; ++nt) {
                        acc[ct][nt] = __builtin_amdgcn_mfma_f32_16x16x32_bf16(
                            ah[ct], zh[nt][ks], acc[ct][nt], 0, 0, 0);
                        acc[ct][nt] = __builtin_amdgcn_mfma_f32_16x16x32_bf16(
                            al[ct], zh[nt][ks], acc[ct][nt], 0, 0, 0);
                        acc[ct][nt] = __builtin_amdgcn_mfma_f32_16x16x32_bf16(
                            ah[ct], zl[nt][ks], acc[ct][nt], 0, 0, 0);
                    }
            }

            // top-2 update: lane holds col n = l16 (row), D row m = quad*4+r (code)
#pragma unroll
            for (int ct = 0; ct < 4; ++ct)
#pragma unroll
                for (int nt = 0; nt < 2; ++nt)
#pragma unroll
                    for (int r = 0; r < 4; ++r) {
                        int cl = cg * 64 + ct * 16 + quad * 4 + r;
                        float s = lds_en[cl] - 2.0f * acc[ct][nt][r];
                        int code = chunk * CHUNK_CODES + cl;
                        top2_update(s, code, s1[nt], i1[nt], s2[nt], i2[nt]);
                    }
        }
    }

    // Cross-quad merge (each quad held a disjoint code subset)
#pragma unroll
    for (int off = 16; off <= 32; off <<= 1) {
#pragma unroll
        for (int nt = 0; nt < 2; ++nt) {
            float t1 = __shfl_xor(s1[nt], off, 64);
            int   j1 = __shfl_xor(i1[nt], off, 64);
            float t2 = __shfl_xor(s2[nt], off, 64);
            int   j2 = __shfl_xor(i2[nt], off, 64);
            top2_merge(s1[nt], i1[nt], s2[nt], i2[nt], t1, j1, t2, j2);
        }
    }

    if (lane < 16) {
#pragma unroll
        for (int nt = 0; nt < 2; ++nt) {
            int row = blockIdx.x * 128 + wv * 32 + nt * 16 + l16;
            i12[2 * row]     = (unsigned int)i1[nt];
            i12[2 * row + 1] = (unsigned int)i2[nt];
        }
    }
}

// ---------------------------------------------------------------------------
// Epilogue: exact fp32 rescore of top-2, then outputs + segment-sum atomics.
// 2 threads per row (64-dim halves). Grid 512 x 256.
// ---------------------------------------------------------------------------
__global__ __launch_bounds__(256) void vq_epilogue(
    const float* __restrict__ z, const float* __restrict__ emb,
    const float* __restrict__ enorm, const unsigned int* __restrict__ i12,
    float* __restrict__ out_zq, float* __restrict__ out_idx,
    float* __restrict__ bc, float* __restrict__ be, float* __restrict__ loss_acc)
{
    const int tid  = threadIdx.x;
    const int half = tid & 1;
    const int row  = blockIdx.x * 128 + (tid >> 1);

    float4 zr[16];
    const float4* zp = (const float4*)(z + (size_t)row * D_DIM + half * 64);
#pragma unroll
    for (int i = 0; i < 16; ++i) zr[i] = zp[i];

    int j1 = (int)i12[2 * row];
    int j2 = (int)i12[2 * row + 1];

    const float4* e1 = (const float4*)(emb + (size_t)j1 * D_DIM + half * 64);
    const float4* e2 = (const float4*)(emb + (size_t)j2 * D_DIM + half * 64);
    float p1 = 0.f, p2 = 0.f;
#pragma unroll
    for (int i = 0; i < 16; ++i) {
        float4 a = e1[i], b = e2[i], zv = zr[i];
        p1 += zv.x * a.x + zv.y * a.y + zv.z * a.z + zv.w * a.w;
        p2 += zv.x * b.x + zv.y * b.y + zv.z * b.z + zv.w * b.w;
    }
    float d1 = p1 + __shfl_xor(p1, 1, 64);
    float d2 = p2 + __shfl_xor(p2, 1, 64);
    float sc1 = enorm[j1] - 2.0f * d1;
    float sc2 = enorm[j2] - 2.0f * d2;
    int best = (sc2 < sc1 || (sc2 == sc1 && j2 < j1)) ? j2 : j1;

    if (half == 0) {
        out_idx[row] = (float)best;
        atomicAdd(bc + best, 1.0f);
    }

    const float4* eq = (const float4*)(emb + (size_t)best * D_DIM + half * 64);
    float4* oz = (float4*)(out_zq + (size_t)row * D_DIM + half * 64);
    float*  bep = be + (size_t)best * D_DIM + half * 64;

    float ls = 0.f;
#pragma unroll
    for (int i = 0; i < 16; ++i) {
        float4 q = eq[i], zv = zr[i];
        float4 df = {q.x - zv.x, q.y - zv.y, q.z - zv.z, q.w - zv.w};
        ls += df.x * df.x + df.y * df.y + df.z * df.z + df.w * df.w;
        float4 o = {zv.x + df.x, zv.y + df.y, zv.z + df.z, zv.w + df.w};
        oz[i] = o;
        atomicAdd(bep + 4 * i + 0, zv.x);
        atomicAdd(bep + 4 * i + 1, zv.y);
        atomicAdd(bep + 4 * i + 2, zv.z);
        atomicAdd(bep + 4 * i + 3, zv.w);
    }

#pragma unroll
    for (int off = 32; off > 0; off >>= 1) ls += __shfl_down(ls, off, 64);
    if ((tid & 63) == 0) atomicAdd(loss_acc, ls);
}

// ---------------------------------------------------------------------------
__global__ void vq_finalize1(const float* __restrict__ cs, const float* __restrict__ bc,
                             const float* __restrict__ loss_acc,
                             float* __restrict__ out_ncs, float* __restrict__ out_loss,
                             float* __restrict__ smoothed)
{
    __shared__ float red[K_CODES];
    int k = threadIdx.x;
    float ncs = cs[k] * DECAY_F + OMD_F * bc[k];
    out_ncs[k] = ncs;
    red[k] = ncs;
    __syncthreads();
    for (int s = 512; s > 0; s >>= 1) {
        if (k < s) red[k] += red[k + s];
        __syncthreads();
    }
    float n = red[0];
    smoothed[k] = (ncs + EPS_F) / (n + (float)K_CODES * EPS_F) * n;
    if (k == 0) out_loss[0] = loss_acc[0] / (float)((size_t)N_ROWS * D_DIM);
}

__global__ void vq_finalize2(const float* __restrict__ ema_w, const float* __restrict__ be,
                             const float* __restrict__ smoothed,
                             float* __restrict__ out_emb, float* __restrict__ out_ema)
{
    int i = blockIdx.x * blockDim.x + threadIdx.x;
    float e = ema_w[i] * DECAY_F + OMD_F * be[i];
    out_ema[i] = e;
    out_emb[i] = e / smoothed[i >> 7];
}

// ---------------------------------------------------------------------------
extern "C" void kernel_launch(void* const* d_in, const int* in_sizes, int n_in,
                              void* d_out, int out_size, void* d_ws, size_t ws_size,
                              hipStream_t stream) {
    const float* z   = (const float*)d_in[0];
    const float* emb = (const float*)d_in[1];
    const float* cs  = (const float*)d_in[2];
    const float* ema = (const float*)d_in[3];

    float* out    = (float*)d_out;
    float* o_zq   = out;
    float* o_idx  = o_zq + (size_t)N_ROWS * D_DIM;
    float* o_loss = o_idx + N_ROWS;
    float* o_emb  = o_loss + 1;
    float* o_ncs  = o_emb + K_CODES * D_DIM;
    float* o_ema  = o_ncs + K_CODES;

    float* ws = (float*)d_ws;
    float* bc       = ws + WS_BC;
    float* be       = ws + WS_BE;
    float* lacc     = ws + WS_LOSS;
    float* enorm    = ws + WS_ENORM;
    float* smoothed = ws + WS_SMOOTH;
    unsigned int*   i12  = (unsigned int*)(ws + WS_I12);
    unsigned short* eimg = (unsigned short*)(ws + WS_EIMG);

    hipMemsetAsync(d_ws, 0, (size_t)(WS_LOSS + 1) * sizeof(float), stream);
    vq_enorm<<<4, 256, 0, stream>>>(emb, enorm);
    vq_esplit<<<128, 256, 0, stream>>>(emb, eimg);
    vq_score<<<N_ROWS / 128, 256, 0, stream>>>(z, eimg, enorm, i12);
    vq_epilogue<<<N_ROWS / 128, 256, 0, stream>>>(z, emb, enorm, i12,
                                                  o_zq, o_idx, bc, be, lacc);
    vq_finalize1<<<1, K_CODES, 0, stream>>>(cs, bc, lacc, o_ncs, o_loss, smoothed);
    vq_finalize2<<<K_CODES * D_DIM / 256, 256, 0, stream>>>(ema, be, smoothed, o_emb, o_ema);
}

// Round 3
// 483.188 us; speedup vs baseline: 3.6243x; 2.8820x over previous
//
#include <hip/hip_runtime.h>

#define K_CODES 1024
#define D_DIM 128
#define N_ROWS 65536
#define DECAY_F 0.99f
#define OMD_F 0.01f
#define EPS_F 1e-5f

// Padded row for bf16 E images: 128 -> 136 elements (272 B) => bank spread
#define EPAD 136
#define CHUNK_CODES 128
#define N_CHUNKS (K_CODES / CHUNK_CODES)
#define CHUNK_USHORT (2 * CHUNK_CODES * EPAD)   // hi+lo image per chunk = 34816

// ---------------------------------------------------------------------------
// ws layout (float-sized units):
//   WS_ENORM  enorm[1024]
//   WS_SMOOTH smoothed[1024]
//   WS_BE     be[131072]            (fully written by segsum; no zeroing)
//   WS_CNT    cnt[1024] int         (zeroed per call)
//   WS_LOSS   loss[1]               (zeroed per call; adjacent to cnt)
//   WS_OFF    offsets[1024] int
//   WS_CUR    cursor[1024] int
//   WS_FIDX   fidx[65536] u32
//   WS_I12    i12[131072] u32
//   WS_BUCKET bucket[65536] u32
//   WS_EIMG   eimg ushort[8][2][128][136]
// ---------------------------------------------------------------------------
#define WS_ENORM  0
#define WS_SMOOTH 1024
#define WS_BE     2048
#define WS_CNT    133120
#define WS_LOSS   134144
#define WS_OFF    135168
#define WS_CUR    136192
#define WS_FIDX   137216
#define WS_I12    202752
#define WS_BUCKET 333824
#define WS_EIMG   399360

typedef __bf16 bf8_t __attribute__((ext_vector_type(8)));
typedef float  f4_t  __attribute__((ext_vector_type(4)));

__device__ inline unsigned short f2bf_bits(float f) {
    __bf16 h = (__bf16)f;
    return __builtin_bit_cast(unsigned short, h);
}
__device__ inline float bf_bits2f(unsigned short u) {
    __bf16 h = __builtin_bit_cast(__bf16, u);
    return (float)h;
}

// ---------------------------------------------------------------------------
__global__ void vq_enorm(const float* __restrict__ emb, float* __restrict__ enorm) {
    int k = blockIdx.x * blockDim.x + threadIdx.x;
    if (k >= K_CODES) return;
    const float4* e4 = (const float4*)(emb + (size_t)k * D_DIM);
    float s = 0.f;
#pragma unroll
    for (int i = 0; i < D_DIM / 4; ++i) {
        float4 v = e4[i];
        s += v.x * v.x + v.y * v.y + v.z * v.z + v.w * v.w;
    }
    enorm[k] = s;
}

// Split E into bf16 hi/lo padded images: e_img[chunk][split][c][136]
__global__ void vq_esplit(const float* __restrict__ emb, unsigned short* __restrict__ eimg) {
    int t = blockIdx.x * blockDim.x + threadIdx.x;   // 32768 = 1024 codes * 32 quads
    int code = t >> 5;
    int q = t & 31;
    float4 v = ((const float4*)(emb + (size_t)code * D_DIM))[q];
    int chunk = code >> 7, c = code & 127;
    size_t hbase = (size_t)chunk * CHUNK_USHORT + (size_t)c * EPAD + q * 4;
    size_t lbase = hbase + (size_t)CHUNK_CODES * EPAD;
    float vv[4] = {v.x, v.y, v.z, v.w};
    ushort4 hi, lo;
    unsigned short* hp = (unsigned short*)&hi;
    unsigned short* lp = (unsigned short*)&lo;
#pragma unroll
    for (int i = 0; i < 4; ++i) {
        unsigned short hb = f2bf_bits(vv[i]);
        hp[i] = hb;
        lp[i] = f2bf_bits(vv[i] - bf_bits2f(hb));
    }
    *(ushort4*)(eimg + hbase) = hi;
    *(ushort4*)(eimg + lbase) = lo;
}

// ---------------------------------------------------------------------------
// Scoring kernel: per-row top-2 candidate codes via split-bf16 MFMA.
// ---------------------------------------------------------------------------
__device__ inline void top2_update(float s, int code, float& s1, int& i1, float& s2, int& i2) {
    bool b1 = s < s1;
    bool b2 = s < s2;
    s2 = b1 ? s1 : (b2 ? s : s2);
    i2 = b1 ? i1 : (b2 ? code : i2);
    s1 = b1 ? s : s1;
    i1 = b1 ? code : i1;
}

__device__ inline void top2_merge(float& s1, int& i1, float& s2, int& i2,
                                  float t1, int j1, float t2, int j2) {
    bool bf = (t1 < s1) || (t1 == s1 && j1 < i1);
    float ns1 = bf ? t1 : s1;  int ni1 = bf ? j1 : i1;
    float ca  = bf ? s1 : t1;  int ia  = bf ? i1 : j1;
    float cb  = bf ? t2 : s2;  int ib  = bf ? j2 : i2;
    bool bs = (ca < cb) || (ca == cb && ia < ib);
    s1 = ns1; i1 = ni1;
    s2 = bs ? ca : cb; i2 = bs ? ia : ib;
}

__global__ __launch_bounds__(256, 2) void vq_score(
    const float* __restrict__ z, const unsigned short* __restrict__ eimg,
    const float* __restrict__ enorm, unsigned int* __restrict__ i12)
{
    __shared__ __align__(16) unsigned short lds[CHUNK_USHORT];  // 69632 B
    __shared__ float lds_en[CHUNK_CODES];

    const int tid  = threadIdx.x;
    const int wv   = tid >> 6;
    const int lane = tid & 63;
    const int l16  = lane & 15;
    const int quad = lane >> 4;

    // Resident z fragments: rows = block*128 + wv*32 + nt*16 + l16
    bf8_t zh[2][4], zl[2][4];
#pragma unroll
    for (int nt = 0; nt < 2; ++nt) {
        int row = blockIdx.x * 128 + wv * 32 + nt * 16 + l16;
        const float* zr = z + (size_t)row * D_DIM;
#pragma unroll
        for (int ks = 0; ks < 4; ++ks) {
            const float4* p = (const float4*)(zr + ks * 32 + quad * 8);
            float4 a = p[0], b = p[1];
            float v[8] = {a.x, a.y, a.z, a.w, b.x, b.y, b.z, b.w};
#pragma unroll
            for (int i = 0; i < 8; ++i) {
                __bf16 hh = (__bf16)v[i];
                zh[nt][ks][i] = hh;
                zl[nt][ks][i] = (__bf16)(v[i] - (float)hh);
            }
        }
    }

    float s1[2] = {3.4e38f, 3.4e38f}, s2[2] = {3.4e38f, 3.4e38f};
    int   i1[2] = {0, 0},             i2[2] = {0, 0};

    for (int chunk = 0; chunk < N_CHUNKS; ++chunk) {
        __syncthreads();
        {
            const uint4* src = (const uint4*)(eimg + (size_t)chunk * CHUNK_USHORT);
            uint4* dst = (uint4*)lds;
#pragma unroll
            for (int i = 0; i < 17; ++i) dst[tid + 256 * i] = src[tid + 256 * i];
            if (tid < CHUNK_CODES) lds_en[tid] = enorm[chunk * CHUNK_CODES + tid];
        }
        __syncthreads();

#pragma unroll
        for (int cg = 0; cg < 2; ++cg) {
            f4_t acc[4][2];
#pragma unroll
            for (int ct = 0; ct < 4; ++ct)
#pragma unroll
                for (int nt = 0; nt < 2; ++nt) acc[ct][nt] = (f4_t)(0.f);

#pragma unroll
            for (int ks = 0; ks < 4; ++ks) {
                bf8_t ah[4], al[4];
#pragma unroll
                for (int ct = 0; ct < 4; ++ct) {
                    int cl = cg * 64 + ct * 16 + l16;
                    int base = cl * EPAD + ks * 32 + quad * 8;
                    ah[ct] = *(const bf8_t*)&lds[base];
                    al[ct] = *(const bf8_t*)&lds[CHUNK_CODES * EPAD + base];
                }
#pragma unroll
                for (int ct = 0; ct < 4; ++ct)
#pragma unroll
                    for (int nt = 0; nt < 2; ++nt) {
                        acc[ct][nt] = __builtin_amdgcn_mfma_f32_16x16x32_bf16(
                            ah[ct], zh[nt][ks], acc[ct][nt], 0, 0, 0);
                        acc[ct][nt] = __builtin_amdgcn_mfma_f32_16x16x32_bf16(
                            al[ct], zh[nt][ks], acc[ct][nt], 0, 0, 0);
                        acc[ct][nt] = __builtin_amdgcn_mfma_f32_16x16x32_bf16(
                            ah[ct], zl[nt][ks], acc[ct][nt], 0, 0, 0);
                    }
            }

#pragma unroll
            for (int ct = 0; ct < 4; ++ct)
#pragma unroll
                for (int nt = 0; nt < 2; ++nt)
#pragma unroll
                    for (int r = 0; r < 4; ++r) {
                        int cl = cg * 64 + ct * 16 + quad * 4 + r;
                        float s = lds_en[cl] - 2.0f * acc[ct][nt][r];
                        int code = chunk * CHUNK_CODES + cl;
                        top2_update(s, code, s1[nt], i1[nt], s2[nt], i2[nt]);
                    }
        }
    }

#pragma unroll
    for (int off = 16; off <= 32; off <<= 1) {
#pragma unroll
        for (int nt = 0; nt < 2; ++nt) {
            float t1 = __shfl_xor(s1[nt], off, 64);
            int   j1 = __shfl_xor(i1[nt], off, 64);
            float t2 = __shfl_xor(s2[nt], off, 64);
            int   j2 = __shfl_xor(i2[nt], off, 64);
            top2_merge(s1[nt], i1[nt], s2[nt], i2[nt], t1, j1, t2, j2);
        }
    }

    if (lane < 16) {
#pragma unroll
        for (int nt = 0; nt < 2; ++nt) {
            int row = blockIdx.x * 128 + wv * 32 + nt * 16 + l16;
            i12[2 * row]     = (unsigned int)i1[nt];
            i12[2 * row + 1] = (unsigned int)i2[nt];
        }
    }
}

// ---------------------------------------------------------------------------
// Decide: exact fp32 rescore of top-2; outputs z_q/idx/loss; int code counts.
// 2 threads per row. Grid 512 x 256. NO float atomics.
// ---------------------------------------------------------------------------
__global__ __launch_bounds__(256) void vq_decide(
    const float* __restrict__ z, const float* __restrict__ emb,
    const float* __restrict__ enorm, const unsigned int* __restrict__ i12,
    float* __restrict__ out_zq, float* __restrict__ out_idx,
    int* __restrict__ cnt, unsigned int* __restrict__ fidx,
    float* __restrict__ loss_acc)
{
    const int tid  = threadIdx.x;
    const int half = tid & 1;
    const int row  = blockIdx.x * 128 + (tid >> 1);

    float4 zr[16];
    const float4* zp = (const float4*)(z + (size_t)row * D_DIM + half * 64);
#pragma unroll
    for (int i = 0; i < 16; ++i) zr[i] = zp[i];

    int j1 = (int)i12[2 * row];
    int j2 = (int)i12[2 * row + 1];

    const float4* e1 = (const float4*)(emb + (size_t)j1 * D_DIM + half * 64);
    const float4* e2 = (const float4*)(emb + (size_t)j2 * D_DIM + half * 64);
    float p1 = 0.f, p2 = 0.f;
#pragma unroll
    for (int i = 0; i < 16; ++i) {
        float4 a = e1[i], b = e2[i], zv = zr[i];
        p1 += zv.x * a.x + zv.y * a.y + zv.z * a.z + zv.w * a.w;
        p2 += zv.x * b.x + zv.y * b.y + zv.z * b.z + zv.w * b.w;
    }
    float d1 = p1 + __shfl_xor(p1, 1, 64);
    float d2 = p2 + __shfl_xor(p2, 1, 64);
    float sc1 = enorm[j1] - 2.0f * d1;
    float sc2 = enorm[j2] - 2.0f * d2;
    int best = (sc2 < sc1 || (sc2 == sc1 && j2 < j1)) ? j2 : j1;

    if (half == 0) {
        out_idx[row] = (float)best;
        fidx[row] = (unsigned int)best;
        atomicAdd(cnt + best, 1);
    }

    const float4* eq = (const float4*)(emb + (size_t)best * D_DIM + half * 64);
    float4* oz = (float4*)(out_zq + (size_t)row * D_DIM + half * 64);

    float ls = 0.f;
#pragma unroll
    for (int i = 0; i < 16; ++i) {
        float4 q = eq[i], zv = zr[i];
        float4 df = {q.x - zv.x, q.y - zv.y, q.z - zv.z, q.w - zv.w};
        ls += df.x * df.x + df.y * df.y + df.z * df.z + df.w * df.w;
        float4 o = {zv.x + df.x, zv.y + df.y, zv.z + df.z, zv.w + df.w};
        oz[i] = o;
    }

#pragma unroll
    for (int off = 32; off > 0; off >>= 1) ls += __shfl_down(ls, off, 64);
    if ((tid & 63) == 0) atomicAdd(loss_acc, ls);
}

// ---------------------------------------------------------------------------
// Exclusive scan of cnt[1024] -> offsets, cursor
// ---------------------------------------------------------------------------
__global__ void vq_scan(const int* __restrict__ cnt, int* __restrict__ offsets,
                        int* __restrict__ cursor)
{
    __shared__ int tmp[K_CODES];
    int k = threadIdx.x;
    int c = cnt[k];
    tmp[k] = c;
    __syncthreads();
    for (int off = 1; off < K_CODES; off <<= 1) {
        int t = (k >= off) ? tmp[k - off] : 0;
        __syncthreads();
        tmp[k] += t;
        __syncthreads();
    }
    int ex = tmp[k] - c;
    offsets[k] = ex;
    cursor[k]  = ex;
}

__global__ void vq_scatter(const unsigned int* __restrict__ fidx,
                           int* __restrict__ cursor, unsigned int* __restrict__ bucket)
{
    int row = blockIdx.x * blockDim.x + threadIdx.x;
    int k = (int)fidx[row];
    int slot = atomicAdd(cursor + k, 1);
    bucket[slot] = (unsigned int)row;
}

// ---------------------------------------------------------------------------
// Segment sum: block k sums z-rows of bucket k. 128 threads = 1 dim each.
// ---------------------------------------------------------------------------
__global__ __launch_bounds__(128) void vq_segsum(
    const float* __restrict__ z, const unsigned int* __restrict__ bucket,
    const int* __restrict__ offsets, const int* __restrict__ cnt,
    float* __restrict__ be)
{
    int k = blockIdx.x;
    int d = threadIdx.x;
    int beg = offsets[k];
    int n = cnt[k];
    float acc = 0.f;
    int i = 0;
    for (; i + 4 <= n; i += 4) {
        unsigned int r0 = bucket[beg + i];
        unsigned int r1 = bucket[beg + i + 1];
        unsigned int r2 = bucket[beg + i + 2];
        unsigned int r3 = bucket[beg + i + 3];
        float v0 = z[(size_t)r0 * D_DIM + d];
        float v1 = z[(size_t)r1 * D_DIM + d];
        float v2 = z[(size_t)r2 * D_DIM + d];
        float v3 = z[(size_t)r3 * D_DIM + d];
        acc += v0 + v1 + v2 + v3;
    }
    for (; i < n; ++i) acc += z[(size_t)bucket[beg + i] * D_DIM + d];
    be[(size_t)k * D_DIM + d] = acc;
}

// ---------------------------------------------------------------------------
__global__ void vq_finalize1(const float* __restrict__ cs, const int* __restrict__ cnt,
                             const float* __restrict__ loss_acc,
                             float* __restrict__ out_ncs, float* __restrict__ out_loss,
                             float* __restrict__ smoothed)
{
    __shared__ float red[K_CODES];
    int k = threadIdx.x;
    float ncs = cs[k] * DECAY_F + OMD_F * (float)cnt[k];
    out_ncs[k] = ncs;
    red[k] = ncs;
    __syncthreads();
    for (int s = 512; s > 0; s >>= 1) {
        if (k < s) red[k] += red[k + s];
        __syncthreads();
    }
    float n = red[0];
    smoothed[k] = (ncs + EPS_F) / (n + (float)K_CODES * EPS_F) * n;
    if (k == 0) out_loss[0] = loss_acc[0] / (float)((size_t)N_ROWS * D_DIM);
}

__global__ void vq_finalize2(const float* __restrict__ ema_w, const float* __restrict__ be,
                             const float* __restrict__ smoothed,
                             float* __restrict__ out_emb, float* __restrict__ out_ema)
{
    int i = blockIdx.x * blockDim.x + threadIdx.x;
    float e = ema_w[i] * DECAY_F + OMD_F * be[i];
    out_ema[i] = e;
    out_emb[i] = e / smoothed[i >> 7];
}

// ---------------------------------------------------------------------------
extern "C" void kernel_launch(void* const* d_in, const int* in_sizes, int n_in,
                              void* d_out, int out_size, void* d_ws, size_t ws_size,
                              hipStream_t stream) {
    const float* z   = (const float*)d_in[0];
    const float* emb = (const float*)d_in[1];
    const float* cs  = (const float*)d_in[2];
    const float* ema = (const float*)d_in[3];

    float* out    = (float*)d_out;
    float* o_zq   = out;
    float* o_idx  = o_zq + (size_t)N_ROWS * D_DIM;
    float* o_loss = o_idx + N_ROWS;
    float* o_emb  = o_loss + 1;
    float* o_ncs  = o_emb + K_CODES * D_DIM;
    float* o_ema  = o_ncs + K_CODES;

    float* ws = (float*)d_ws;
    float*          enorm    = ws + WS_ENORM;
    float*          smoothed = ws + WS_SMOOTH;
    float*          be       = ws + WS_BE;
    int*            cnt      = (int*)(ws + WS_CNT);
    float*          lacc     = ws + WS_LOSS;
    int*            offsets  = (int*)(ws + WS_OFF);
    int*            cursor   = (int*)(ws + WS_CUR);
    unsigned int*   fidx     = (unsigned int*)(ws + WS_FIDX);
    unsigned int*   i12      = (unsigned int*)(ws + WS_I12);
    unsigned int*   bucket   = (unsigned int*)(ws + WS_BUCKET);
    unsigned short* eimg     = (unsigned short*)(ws + WS_EIMG);

    // zero cnt[1024] + loss[1] (contiguous)
    hipMemsetAsync(ws + WS_CNT, 0, (K_CODES + 1) * sizeof(float), stream);
    vq_enorm<<<4, 256, 0, stream>>>(emb, enorm);
    vq_esplit<<<128, 256, 0, stream>>>(emb, eimg);
    vq_score<<<N_ROWS / 128, 256, 0, stream>>>(z, eimg, enorm, i12);
    vq_decide<<<N_ROWS / 128, 256, 0, stream>>>(z, emb, enorm, i12,
                                                o_zq, o_idx, cnt, fidx, lacc);
    vq_scan<<<1, K_CODES, 0, stream>>>(cnt, offsets, cursor);
    vq_scatter<<<N_ROWS / 256, 256, 0, stream>>>(fidx, cursor, bucket);
    vq_segsum<<<K_CODES, 128, 0, stream>>>(z, bucket, offsets, cnt, be);
    vq_finalize1<<<1, K_CODES, 0, stream>>>(cs, cnt, lacc, o_ncs, o_loss, smoothed);
    vq_finalize2<<<K_CODES * D_DIM / 256, 256, 0, stream>>>(ema, be, smoothed, o_emb, o_ema);
}

// Round 4
// 248.797 us; speedup vs baseline: 7.0387x; 1.9421x over previous
//
#include <hip/hip_runtime.h>

#define K_CODES 1024
#define D_DIM 128
#define N_ROWS 65536
#define DECAY_F 0.99f
#define OMD_F 0.01f
#define EPS_F 1e-5f

// Padded row for bf16 E images: 128 -> 136 elements (272 B) => bank spread
#define EPAD 136
#define CHUNK_CODES 128
#define N_CHUNKS (K_CODES / CHUNK_CODES)
#define CHUNK_USHORT (2 * CHUNK_CODES * EPAD)   // hi+lo image per chunk = 34816

#define SEG_TILE 64   // bucket slots per segsum block

// ---------------------------------------------------------------------------
// ws layout (float-sized units):
//   WS_ENORM  enorm[1024]
//   WS_SMOOTH smoothed[1024]
//   WS_BE     be[131072] (zeroed per call; atomic-accumulated)
//   WS_CNT    cnt[1024] int (zeroed per call)
//   WS_LOSS   loss[1]       (zeroed per call; adjacent to cnt)
//   WS_CUR    cursor[1024] int
//   WS_FIDX   fidx[65536] u32
//   WS_I12    i12[131072] u32
//   WS_BUCKET bucket[65536] u32
//   WS_SCODE  scode[65536] int
//   WS_EIMG   eimg ushort[8][2][128][136]
// ---------------------------------------------------------------------------
#define WS_ENORM  0
#define WS_SMOOTH 1024
#define WS_BE     2048
#define WS_CNT    133120
#define WS_LOSS   134144
#define WS_CUR    134160
#define WS_FIDX   135184
#define WS_I12    200720
#define WS_BUCKET 331792
#define WS_SCODE  397328
#define WS_EIMG   462864

typedef __bf16 bf8_t __attribute__((ext_vector_type(8)));
typedef float  f4_t  __attribute__((ext_vector_type(4)));

__device__ inline unsigned short f2bf_bits(float f) {
    __bf16 h = (__bf16)f;
    return __builtin_bit_cast(unsigned short, h);
}
__device__ inline float bf_bits2f(unsigned short u) {
    __bf16 h = __builtin_bit_cast(__bf16, u);
    return (float)h;
}

// ---------------------------------------------------------------------------
__global__ void vq_enorm(const float* __restrict__ emb, float* __restrict__ enorm) {
    int k = blockIdx.x * blockDim.x + threadIdx.x;
    if (k >= K_CODES) return;
    const float4* e4 = (const float4*)(emb + (size_t)k * D_DIM);
    float s = 0.f;
#pragma unroll
    for (int i = 0; i < D_DIM / 4; ++i) {
        float4 v = e4[i];
        s += v.x * v.x + v.y * v.y + v.z * v.z + v.w * v.w;
    }
    enorm[k] = s;
}

// Split E into bf16 hi/lo padded images: e_img[chunk][split][c][136]
__global__ void vq_esplit(const float* __restrict__ emb, unsigned short* __restrict__ eimg) {
    int t = blockIdx.x * blockDim.x + threadIdx.x;   // 32768 = 1024 codes * 32 quads
    int code = t >> 5;
    int q = t & 31;
    float4 v = ((const float4*)(emb + (size_t)code * D_DIM))[q];
    int chunk = code >> 7, c = code & 127;
    size_t hbase = (size_t)chunk * CHUNK_USHORT + (size_t)c * EPAD + q * 4;
    size_t lbase = hbase + (size_t)CHUNK_CODES * EPAD;
    float vv[4] = {v.x, v.y, v.z, v.w};
    ushort4 hi, lo;
    unsigned short* hp = (unsigned short*)&hi;
    unsigned short* lp = (unsigned short*)&lo;
#pragma unroll
    for (int i = 0; i < 4; ++i) {
        unsigned short hb = f2bf_bits(vv[i]);
        hp[i] = hb;
        lp[i] = f2bf_bits(vv[i] - bf_bits2f(hb));
    }
    *(ushort4*)(eimg + hbase) = hi;
    *(ushort4*)(eimg + lbase) = lo;
}

// ---------------------------------------------------------------------------
// Scoring kernel: per-row top-2 candidate codes via split-bf16 MFMA.
// ---------------------------------------------------------------------------
__device__ inline void top2_update(float s, int code, float& s1, int& i1, float& s2, int& i2) {
    bool b1 = s < s1;
    bool b2 = s < s2;
    s2 = b1 ? s1 : (b2 ? s : s2);
    i2 = b1 ? i1 : (b2 ? code : i2);
    s1 = b1 ? s : s1;
    i1 = b1 ? code : i1;
}

__device__ inline void top2_merge(float& s1, int& i1, float& s2, int& i2,
                                  float t1, int j1, float t2, int j2) {
    bool bf = (t1 < s1) || (t1 == s1 && j1 < i1);
    float ns1 = bf ? t1 : s1;  int ni1 = bf ? j1 : i1;
    float ca  = bf ? s1 : t1;  int ia  = bf ? i1 : j1;
    float cb  = bf ? t2 : s2;  int ib  = bf ? j2 : i2;
    bool bs = (ca < cb) || (ca == cb && ia < ib);
    s1 = ns1; i1 = ni1;
    s2 = bs ? ca : cb; i2 = bs ? ia : ib;
}

__global__ __launch_bounds__(256, 2) void vq_score(
    const float* __restrict__ z, const unsigned short* __restrict__ eimg,
    const float* __restrict__ enorm, unsigned int* __restrict__ i12)
{
    __shared__ __align__(16) unsigned short lds[CHUNK_USHORT];  // 69632 B
    __shared__ float lds_en[CHUNK_CODES];

    const int tid  = threadIdx.x;
    const int wv   = tid >> 6;
    const int lane = tid & 63;
    const int l16  = lane & 15;
    const int quad = lane >> 4;

    bf8_t zh[2][4], zl[2][4];
#pragma unroll
    for (int nt = 0; nt < 2; ++nt) {
        int row = blockIdx.x * 128 + wv * 32 + nt * 16 + l16;
        const float* zr = z + (size_t)row * D_DIM;
#pragma unroll
        for (int ks = 0; ks < 4; ++ks) {
            const float4* p = (const float4*)(zr + ks * 32 + quad * 8);
            float4 a = p[0], b = p[1];
            float v[8] = {a.x, a.y, a.z, a.w, b.x, b.y, b.z, b.w};
#pragma unroll
            for (int i = 0; i < 8; ++i) {
                __bf16 hh = (__bf16)v[i];
                zh[nt][ks][i] = hh;
                zl[nt][ks][i] = (__bf16)(v[i] - (float)hh);
            }
        }
    }

    float s1[2] = {3.4e38f, 3.4e38f}, s2[2] = {3.4e38f, 3.4e38f};
    int   i1[2] = {0, 0},             i2[2] = {0, 0};

    for (int chunk = 0; chunk < N_CHUNKS; ++chunk) {
        __syncthreads();
        {
            const uint4* src = (const uint4*)(eimg + (size_t)chunk * CHUNK_USHORT);
            uint4* dst = (uint4*)lds;
#pragma unroll
            for (int i = 0; i < 17; ++i) dst[tid + 256 * i] = src[tid + 256 * i];
            if (tid < CHUNK_CODES) lds_en[tid] = enorm[chunk * CHUNK_CODES + tid];
        }
        __syncthreads();

#pragma unroll
        for (int cg = 0; cg < 2; ++cg) {
            f4_t acc[4][2];
#pragma unroll
            for (int ct = 0; ct < 4; ++ct)
#pragma unroll
                for (int nt = 0; nt < 2; ++nt) acc[ct][nt] = (f4_t)(0.f);

#pragma unroll
            for (int ks = 0; ks < 4; ++ks) {
                bf8_t ah[4], al[4];
#pragma unroll
                for (int ct = 0; ct < 4; ++ct) {
                    int cl = cg * 64 + ct * 16 + l16;
                    int base = cl * EPAD + ks * 32 + quad * 8;
                    ah[ct] = *(const bf8_t*)&lds[base];
                    al[ct] = *(const bf8_t*)&lds[CHUNK_CODES * EPAD + base];
                }
#pragma unroll
                for (int ct = 0; ct < 4; ++ct)
#pragma unroll
                    for (int nt = 0; nt < 2; ++nt) {
                        acc[ct][nt] = __builtin_amdgcn_mfma_f32_16x16x32_bf16(
                            ah[ct], zh[nt][ks], acc[ct][nt], 0, 0, 0);
                        acc[ct][nt] = __builtin_amdgcn_mfma_f32_16x16x32_bf16(
                            al[ct], zh[nt][ks], acc[ct][nt], 0, 0, 0);
                        acc[ct][nt] = __builtin_amdgcn_mfma_f32_16x16x32_bf16(
                            ah[ct], zl[nt][ks], acc[ct][nt], 0, 0, 0);
                    }
            }

#pragma unroll
            for (int ct = 0; ct < 4; ++ct)
#pragma unroll
                for (int nt = 0; nt < 2; ++nt)
#pragma unroll
                    for (int r = 0; r < 4; ++r) {
                        int cl = cg * 64 + ct * 16 + quad * 4 + r;
                        float s = lds_en[cl] - 2.0f * acc[ct][nt][r];
                        int code = chunk * CHUNK_CODES + cl;
                        top2_update(s, code, s1[nt], i1[nt], s2[nt], i2[nt]);
                    }
        }
    }

#pragma unroll
    for (int off = 16; off <= 32; off <<= 1) {
#pragma unroll
        for (int nt = 0; nt < 2; ++nt) {
            float t1 = __shfl_xor(s1[nt], off, 64);
            int   j1 = __shfl_xor(i1[nt], off, 64);
            float t2 = __shfl_xor(s2[nt], off, 64);
            int   j2 = __shfl_xor(i2[nt], off, 64);
            top2_merge(s1[nt], i1[nt], s2[nt], i2[nt], t1, j1, t2, j2);
        }
    }

    if (lane < 16) {
#pragma unroll
        for (int nt = 0; nt < 2; ++nt) {
            int row = blockIdx.x * 128 + wv * 32 + nt * 16 + l16;
            i12[2 * row]     = (unsigned int)i1[nt];
            i12[2 * row + 1] = (unsigned int)i2[nt];
        }
    }
}

// ---------------------------------------------------------------------------
// Decide: exact fp32 rescore of top-2; outputs z_q/idx/loss; int code counts.
// ---------------------------------------------------------------------------
__global__ __launch_bounds__(256) void vq_decide(
    const float* __restrict__ z, const float* __restrict__ emb,
    const float* __restrict__ enorm, const unsigned int* __restrict__ i12,
    float* __restrict__ out_zq, float* __restrict__ out_idx,
    int* __restrict__ cnt, unsigned int* __restrict__ fidx,
    float* __restrict__ loss_acc)
{
    const int tid  = threadIdx.x;
    const int half = tid & 1;
    const int row  = blockIdx.x * 128 + (tid >> 1);

    float4 zr[16];
    const float4* zp = (const float4*)(z + (size_t)row * D_DIM + half * 64);
#pragma unroll
    for (int i = 0; i < 16; ++i) zr[i] = zp[i];

    int j1 = (int)i12[2 * row];
    int j2 = (int)i12[2 * row + 1];

    const float4* e1 = (const float4*)(emb + (size_t)j1 * D_DIM + half * 64);
    const float4* e2 = (const float4*)(emb + (size_t)j2 * D_DIM + half * 64);
    float p1 = 0.f, p2 = 0.f;
#pragma unroll
    for (int i = 0; i < 16; ++i) {
        float4 a = e1[i], b = e2[i], zv = zr[i];
        p1 += zv.x * a.x + zv.y * a.y + zv.z * a.z + zv.w * a.w;
        p2 += zv.x * b.x + zv.y * b.y + zv.z * b.z + zv.w * b.w;
    }
    float d1 = p1 + __shfl_xor(p1, 1, 64);
    float d2 = p2 + __shfl_xor(p2, 1, 64);
    float sc1 = enorm[j1] - 2.0f * d1;
    float sc2 = enorm[j2] - 2.0f * d2;
    int best = (sc2 < sc1 || (sc2 == sc1 && j2 < j1)) ? j2 : j1;

    if (half == 0) {
        out_idx[row] = (float)best;
        fidx[row] = (unsigned int)best;
        atomicAdd(cnt + best, 1);
    }

    const float4* eq = (const float4*)(emb + (size_t)best * D_DIM + half * 64);
    float4* oz = (float4*)(out_zq + (size_t)row * D_DIM + half * 64);

    float ls = 0.f;
#pragma unroll
    for (int i = 0; i < 16; ++i) {
        float4 q = eq[i], zv = zr[i];
        float4 df = {q.x - zv.x, q.y - zv.y, q.z - zv.z, q.w - zv.w};
        ls += df.x * df.x + df.y * df.y + df.z * df.z + df.w * df.w;
        float4 o = {zv.x + df.x, zv.y + df.y, zv.z + df.z, zv.w + df.w};
        oz[i] = o;
    }

#pragma unroll
    for (int off = 32; off > 0; off >>= 1) ls += __shfl_down(ls, off, 64);
    if ((tid & 63) == 0) atomicAdd(loss_acc, ls);
}

// ---------------------------------------------------------------------------
// Exclusive scan of cnt[1024] -> cursor
// ---------------------------------------------------------------------------
__global__ void vq_scan(const int* __restrict__ cnt, int* __restrict__ cursor)
{
    __shared__ int tmp[K_CODES];
    int k = threadIdx.x;
    int c = cnt[k];
    tmp[k] = c;
    __syncthreads();
    for (int off = 1; off < K_CODES; off <<= 1) {
        int t = (k >= off) ? tmp[k - off] : 0;
        __syncthreads();
        tmp[k] += t;
        __syncthreads();
    }
    cursor[k] = tmp[k] - c;
}

__global__ void vq_scatter(const unsigned int* __restrict__ fidx,
                           int* __restrict__ cursor, unsigned int* __restrict__ bucket,
                           int* __restrict__ scode)
{
    int row = blockIdx.x * blockDim.x + threadIdx.x;
    int k = (int)fidx[row];
    int slot = atomicAdd(cursor + k, 1);
    bucket[slot] = (unsigned int)row;
    scode[slot]  = k;
}

// ---------------------------------------------------------------------------
// Skew-oblivious segment sum: each block handles SEG_TILE consecutive bucket
// slots (sorted by code); segmented accumulate, atomicAdd flush per segment.
// Grid 1024 x 128 threads (thread = dim).
// ---------------------------------------------------------------------------
__global__ __launch_bounds__(128) void vq_segsum(
    const float* __restrict__ z, const unsigned int* __restrict__ bucket,
    const int* __restrict__ scode, float* __restrict__ be)
{
    __shared__ int sb[SEG_TILE];
    __shared__ int sc[SEG_TILE];
    const int tid = threadIdx.x;
    const int t0  = blockIdx.x * SEG_TILE;

    if (tid < SEG_TILE) sb[tid] = (int)bucket[t0 + tid];
    else if (tid < 2 * SEG_TILE) sc[tid - SEG_TILE] = scode[t0 + tid - SEG_TILE];
    __syncthreads();

    const int d = tid;   // 0..127
    float acc = 0.f;
    int cur = sc[0];

    for (int i = 0; i < SEG_TILE; i += 8) {
        float v[8];
#pragma unroll
        for (int j = 0; j < 8; ++j)
            v[j] = z[(size_t)sb[i + j] * D_DIM + d];   // 8 independent loads
#pragma unroll
        for (int j = 0; j < 8; ++j) {
            int c = sc[i + j];                          // thread-uniform
            if (c != cur) {
                atomicAdd(be + (size_t)cur * D_DIM + d, acc);
                acc = 0.f;
                cur = c;
            }
            acc += v[j];
        }
    }
    atomicAdd(be + (size_t)cur * D_DIM + d, acc);
}

// ---------------------------------------------------------------------------
__global__ void vq_finalize1(const float* __restrict__ cs, const int* __restrict__ cnt,
                             const float* __restrict__ loss_acc,
                             float* __restrict__ out_ncs, float* __restrict__ out_loss,
                             float* __restrict__ smoothed)
{
    __shared__ float red[K_CODES];
    int k = threadIdx.x;
    float ncs = cs[k] * DECAY_F + OMD_F * (float)cnt[k];
    out_ncs[k] = ncs;
    red[k] = ncs;
    __syncthreads();
    for (int s = 512; s > 0; s >>= 1) {
        if (k < s) red[k] += red[k + s];
        __syncthreads();
    }
    float n = red[0];
    smoothed[k] = (ncs + EPS_F) / (n + (float)K_CODES * EPS_F) * n;
    if (k == 0) out_loss[0] = loss_acc[0] / (float)((size_t)N_ROWS * D_DIM);
}

__global__ void vq_finalize2(const float* __restrict__ ema_w, const float* __restrict__ be,
                             const float* __restrict__ smoothed,
                             float* __restrict__ out_emb, float* __restrict__ out_ema)
{
    int i = blockIdx.x * blockDim.x + threadIdx.x;
    float e = ema_w[i] * DECAY_F + OMD_F * be[i];
    out_ema[i] = e;
    out_emb[i] = e / smoothed[i >> 7];
}

// ---------------------------------------------------------------------------
extern "C" void kernel_launch(void* const* d_in, const int* in_sizes, int n_in,
                              void* d_out, int out_size, void* d_ws, size_t ws_size,
                              hipStream_t stream) {
    const float* z   = (const float*)d_in[0];
    const float* emb = (const float*)d_in[1];
    const float* cs  = (const float*)d_in[2];
    const float* ema = (const float*)d_in[3];

    float* out    = (float*)d_out;
    float* o_zq   = out;
    float* o_idx  = o_zq + (size_t)N_ROWS * D_DIM;
    float* o_loss = o_idx + N_ROWS;
    float* o_emb  = o_loss + 1;
    float* o_ncs  = o_emb + K_CODES * D_DIM;
    float* o_ema  = o_ncs + K_CODES;

    float* ws = (float*)d_ws;
    float*          enorm    = ws + WS_ENORM;
    float*          smoothed = ws + WS_SMOOTH;
    float*          be       = ws + WS_BE;
    int*            cnt      = (int*)(ws + WS_CNT);
    float*          lacc     = ws + WS_LOSS;
    int*            cursor   = (int*)(ws + WS_CUR);
    unsigned int*   fidx     = (unsigned int*)(ws + WS_FIDX);
    unsigned int*   i12      = (unsigned int*)(ws + WS_I12);
    unsigned int*   bucket   = (unsigned int*)(ws + WS_BUCKET);
    int*            scode    = (int*)(ws + WS_SCODE);
    unsigned short* eimg     = (unsigned short*)(ws + WS_EIMG);

    // zero cnt[1024]+loss[1] (contiguous) and be[131072]
    hipMemsetAsync(ws + WS_CNT, 0, (K_CODES + 1) * sizeof(float), stream);
    hipMemsetAsync(ws + WS_BE, 0, (size_t)K_CODES * D_DIM * sizeof(float), stream);
    vq_enorm<<<4, 256, 0, stream>>>(emb, enorm);
    vq_esplit<<<128, 256, 0, stream>>>(emb, eimg);
    vq_score<<<N_ROWS / 128, 256, 0, stream>>>(z, eimg, enorm, i12);
    vq_decide<<<N_ROWS / 128, 256, 0, stream>>>(z, emb, enorm, i12,
                                                o_zq, o_idx, cnt, fidx, lacc);
    vq_scan<<<1, K_CODES, 0, stream>>>(cnt, cursor);
    vq_scatter<<<N_ROWS / 256, 256, 0, stream>>>(fidx, cursor, bucket, scode);
    vq_segsum<<<N_ROWS / SEG_TILE, 128, 0, stream>>>(z, bucket, scode, be);
    vq_finalize1<<<1, K_CODES, 0, stream>>>(cs, cnt, lacc, o_ncs, o_loss, smoothed);
    vq_finalize2<<<K_CODES * D_DIM / 256, 256, 0, stream>>>(ema, be, smoothed, o_emb, o_ema);
}

// Round 5
// 222.932 us; speedup vs baseline: 7.8553x; 1.1160x over previous
//
#include <hip/hip_runtime.h>

#define K_CODES 1024
#define D_DIM 128
#define N_ROWS 65536
#define DECAY_F 0.99f
#define OMD_F 0.01f
#define EPS_F 1e-5f

#define EPAD 136                       // padded bf16 row: 272 B -> conflict-free-ish
#define CHUNK_CODES 128
#define N_CHUNKS 8
#define CHUNK_USHORT (2 * CHUNK_CODES * EPAD)   // 34816 ushorts = 69632 B
#define NT 4                           // row tiles per wave
#define SEG_TILE 64

// ---------------------------------------------------------------------------
// ws layout (float units). [WS_CNT, WS_ZERO_END) zeroed by ONE memset.
//   cnt[1024] int | loss[1] | pad[3] | be[131072] | enorm | smoothed | cursor
//   fidx[65536] | bucket[65536] | scode[65536] | eimg ushort[8][2][128][136]
// ---------------------------------------------------------------------------
#define WS_CNT     0
#define WS_LOSS    1024
#define WS_BE      1028
#define WS_ZERO_END (1028 + 131072)    // 132100 floats zeroed per call
#define WS_ENORM   132100
#define WS_SMOOTH  133124
#define WS_CUR     134148
#define WS_FIDX    135172
#define WS_BUCKET  200708
#define WS_SCODE   266244
#define WS_EIMG    331780              // byte off 1327120, 16B aligned

typedef __bf16 bf8_t __attribute__((ext_vector_type(8)));
typedef float  f4_t  __attribute__((ext_vector_type(4)));

__device__ inline unsigned short f2bf_bits(float f) {
    __bf16 h = (__bf16)f;
    return __builtin_bit_cast(unsigned short, h);
}
__device__ inline float bf_bits2f(unsigned short u) {
    __bf16 h = __builtin_bit_cast(__bf16, u);
    return (float)h;
}

// async global->LDS, 16 B per lane. lds dest is wave-uniform base (+lane*16 in HW).
__device__ inline void gld16(const void* g, void* l) {
    __builtin_amdgcn_global_load_lds(
        (const __attribute__((address_space(1))) void*)g,
        (__attribute__((address_space(3))) void*)l, 16, 0, 0);
}

// ---------------------------------------------------------------------------
// Prep: enorm + bf16 hi/lo split image, one pass over emb.
// 32 threads per code; grid 128 x 256.
// ---------------------------------------------------------------------------
__global__ void vq_prep(const float* __restrict__ emb, float* __restrict__ enorm,
                        unsigned short* __restrict__ eimg) {
    int t = blockIdx.x * blockDim.x + threadIdx.x;   // 32768
    int code = t >> 5;
    int q = t & 31;
    float4 v = ((const float4*)(emb + (size_t)code * D_DIM))[q];
    int chunk = code >> 7, c = code & 127;
    size_t hbase = (size_t)chunk * CHUNK_USHORT + (size_t)c * EPAD + q * 4;
    size_t lbase = hbase + (size_t)CHUNK_CODES * EPAD;
    float vv[4] = {v.x, v.y, v.z, v.w};
    ushort4 hi, lo;
    unsigned short* hp = (unsigned short*)&hi;
    unsigned short* lp = (unsigned short*)&lo;
#pragma unroll
    for (int i = 0; i < 4; ++i) {
        unsigned short hb = f2bf_bits(vv[i]);
        hp[i] = hb;
        lp[i] = f2bf_bits(vv[i] - bf_bits2f(hb));
    }
    *(ushort4*)(eimg + hbase) = hi;
    *(ushort4*)(eimg + lbase) = lo;

    float s = v.x * v.x + v.y * v.y + v.z * v.z + v.w * v.w;
#pragma unroll
    for (int o = 1; o < 32; o <<= 1) s += __shfl_xor(s, o, 64);
    if (q == 0) enorm[code] = s;
}

// ---------------------------------------------------------------------------
__device__ inline void top2_update(float s, int code, float& s1, int& i1, float& s2, int& i2) {
    bool b1 = s < s1;
    bool b2 = s < s2;
    s2 = b1 ? s1 : (b2 ? s : s2);
    i2 = b1 ? i1 : (b2 ? code : i2);
    s1 = b1 ? s : s1;
    i1 = b1 ? code : i1;
}

__device__ inline void top2_merge(float& s1, int& i1, float& s2, int& i2,
                                  float t1, int j1, float t2, int j2) {
    bool bf = (t1 < s1) || (t1 == s1 && j1 < i1);
    float ns1 = bf ? t1 : s1;  int ni1 = bf ? j1 : i1;
    float ca  = bf ? s1 : t1;  int ia  = bf ? i1 : j1;
    float cb  = bf ? t2 : s2;  int ib  = bf ? j2 : i2;
    bool bs = (ca < cb) || (ca == cb && ia < ib);
    s1 = ns1; i1 = ni1;
    s2 = bs ? ca : cb; i2 = bs ? ia : ib;
}

// ---------------------------------------------------------------------------
// Fused score + decide. Block: 256 thr = 4 waves, nt=4 -> 256 rows/block.
// Grid 256 (1 block/CU). LDS: double-buffered chunk (2x68KB) + enorm (4KB).
// ---------------------------------------------------------------------------
__global__ __launch_bounds__(256) void vq_score(
    const float* __restrict__ z, const unsigned short* __restrict__ eimg,
    const float* __restrict__ enorm_g, const float* __restrict__ emb,
    float* __restrict__ out_zq, float* __restrict__ out_idx,
    int* __restrict__ cnt, unsigned int* __restrict__ fidx,
    float* __restrict__ loss_acc)
{
    __shared__ __align__(16) unsigned short lds[2][CHUNK_USHORT];  // 139264 B
    __shared__ __align__(16) float lds_en[K_CODES];                // 4 KB

    const int tid  = threadIdx.x;
    const int wv   = tid >> 6;
    const int lane = tid & 63;
    const int l16  = lane & 15;
    const int quad = lane >> 4;
    const int rowbase = blockIdx.x * 256 + wv * 64;

    // stage all 1024 enorms once
    ((float4*)lds_en)[tid] = ((const float4*)enorm_g)[tid];

    // async-stage chunk 0 into buf 0 (17 x 1KB per wave)
    {
        const char* gs = (const char*)eimg;
        char* ls = (char*)&lds[0][0];
        int wb = wv * 17408;
#pragma unroll
        for (int i = 0; i < 17; ++i)
            gld16(gs + wb + i * 1024 + lane * 16, ls + wb + i * 1024);
    }

    // resident z fragments (bf16 hi/lo), rows = rowbase + nt*16 + l16
    bf8_t zh[NT][4], zl[NT][4];
#pragma unroll
    for (int nt = 0; nt < NT; ++nt) {
        int row = rowbase + nt * 16 + l16;
        const float* zr = z + (size_t)row * D_DIM;
#pragma unroll
        for (int ks = 0; ks < 4; ++ks) {
            const float4* p = (const float4*)(zr + ks * 32 + quad * 8);
            float4 a = p[0], b = p[1];
            float v[8] = {a.x, a.y, a.z, a.w, b.x, b.y, b.z, b.w};
#pragma unroll
            for (int i = 0; i < 8; ++i) {
                __bf16 hh = (__bf16)v[i];
                zh[nt][ks][i] = hh;
                zl[nt][ks][i] = (__bf16)(v[i] - (float)hh);
            }
        }
    }

    float s1[NT], s2[NT];
    int   i1[NT], i2[NT];
#pragma unroll
    for (int nt = 0; nt < NT; ++nt) { s1[nt] = 3.4e38f; s2[nt] = 3.4e38f; i1[nt] = 0; i2[nt] = 0; }

    __syncthreads();   // drains chunk-0 async loads (vmcnt 0 before barrier)

    for (int c = 0; c < N_CHUNKS; ++c) {
        const int cur = c & 1;
        if (c + 1 < N_CHUNKS) {   // prefetch next chunk into other buffer
            const char* gs = (const char*)(eimg + (size_t)(c + 1) * CHUNK_USHORT);
            char* ls = (char*)&lds[1 - cur][0];
            int wb = wv * 17408;
#pragma unroll
            for (int i = 0; i < 17; ++i)
                gld16(gs + wb + i * 1024 + lane * 16, ls + wb + i * 1024);
        }
        const unsigned short* buf = &lds[cur][0];

#pragma unroll
        for (int cg = 0; cg < 4; ++cg) {     // 32 codes per pass
            f4_t acc[2][NT];
#pragma unroll
            for (int ct = 0; ct < 2; ++ct)
#pragma unroll
                for (int nt = 0; nt < NT; ++nt) acc[ct][nt] = (f4_t)(0.f);

#pragma unroll
            for (int ks = 0; ks < 4; ++ks) {
                bf8_t ah[2], al[2];
#pragma unroll
                for (int ct = 0; ct < 2; ++ct) {
                    int cl = cg * 32 + ct * 16 + l16;
                    int base = cl * EPAD + ks * 32 + quad * 8;
                    ah[ct] = *(const bf8_t*)&buf[base];
                    al[ct] = *(const bf8_t*)&buf[CHUNK_CODES * EPAD + base];
                }
#pragma unroll
                for (int ct = 0; ct < 2; ++ct)
#pragma unroll
                    for (int nt = 0; nt < NT; ++nt) {
                        acc[ct][nt] = __builtin_amdgcn_mfma_f32_16x16x32_bf16(
                            ah[ct], zh[nt][ks], acc[ct][nt], 0, 0, 0);
                        acc[ct][nt] = __builtin_amdgcn_mfma_f32_16x16x32_bf16(
                            al[ct], zh[nt][ks], acc[ct][nt], 0, 0, 0);
                        acc[ct][nt] = __builtin_amdgcn_mfma_f32_16x16x32_bf16(
                            ah[ct], zl[nt][ks], acc[ct][nt], 0, 0, 0);
                    }
            }

#pragma unroll
            for (int ct = 0; ct < 2; ++ct) {
                int cb = c * 128 + cg * 32 + ct * 16 + quad * 4;
                float4 en4 = *(const float4*)&lds_en[cb];
                float env[4] = {en4.x, en4.y, en4.z, en4.w};
#pragma unroll
                for (int nt = 0; nt < NT; ++nt)
#pragma unroll
                    for (int r = 0; r < 4; ++r) {
                        float s = env[r] - 2.0f * acc[ct][nt][r];
                        top2_update(s, cb + r, s1[nt], i1[nt], s2[nt], i2[nt]);
                    }
            }
        }
        __syncthreads();   // all waves done with buf[cur]; prefetch drained
    }

    // cross-quad merge (each quad saw a disjoint code subset)
#pragma unroll
    for (int off = 16; off <= 32; off <<= 1) {
#pragma unroll
        for (int nt = 0; nt < NT; ++nt) {
            float t1 = __shfl_xor(s1[nt], off, 64);
            int   j1 = __shfl_xor(i1[nt], off, 64);
            float t2 = __shfl_xor(s2[nt], off, 64);
            int   j2 = __shfl_xor(i2[nt], off, 64);
            top2_merge(s1[nt], i1[nt], s2[nt], i2[nt], t1, j1, t2, j2);
        }
    }

    // ---------------- fused decide epilogue ----------------
    float ls = 0.f;
#pragma unroll
    for (int nt = 0; nt < NT; ++nt) {
        int row = rowbase + nt * 16 + l16;
        int j1 = i1[nt], j2 = i2[nt];      // uniform across the row's 4 quad-lanes

        const float4* zp  = (const float4*)(z   + (size_t)row * D_DIM);
        const float4* e1p = (const float4*)(emb + (size_t)j1  * D_DIM);
        const float4* e2p = (const float4*)(emb + (size_t)j2  * D_DIM);

        float4 zv[8], a1[8], a2[8];
#pragma unroll
        for (int ks = 0; ks < 4; ++ks) {
            int o = ks * 8 + quad * 2;
            zv[ks * 2]     = zp[o];   zv[ks * 2 + 1] = zp[o + 1];
            a1[ks * 2]     = e1p[o];  a1[ks * 2 + 1] = e1p[o + 1];
            a2[ks * 2]     = e2p[o];  a2[ks * 2 + 1] = e2p[o + 1];
        }
        float p1 = 0.f, p2 = 0.f;
#pragma unroll
        for (int i = 0; i < 8; ++i) {
            p1 += zv[i].x * a1[i].x + zv[i].y * a1[i].y + zv[i].z * a1[i].z + zv[i].w * a1[i].w;
            p2 += zv[i].x * a2[i].x + zv[i].y * a2[i].y + zv[i].z * a2[i].z + zv[i].w * a2[i].w;
        }
        p1 += __shfl_xor(p1, 16, 64); p1 += __shfl_xor(p1, 32, 64);
        p2 += __shfl_xor(p2, 16, 64); p2 += __shfl_xor(p2, 32, 64);
        float sc1 = lds_en[j1] - 2.0f * p1;
        float sc2 = lds_en[j2] - 2.0f * p2;
        bool use2 = (sc2 < sc1) || (sc2 == sc1 && j2 < j1);
        int best = use2 ? j2 : j1;

        if (quad == 0) {
            out_idx[row] = (float)best;
            fidx[row] = (unsigned int)best;
            atomicAdd(cnt + best, 1);
        }

        float4* oz = (float4*)(out_zq + (size_t)row * D_DIM);
#pragma unroll
        for (int i = 0; i < 8; ++i) {
            float4 q = use2 ? a2[i] : a1[i];
            float4 zvv = zv[i];
            float4 df = {q.x - zvv.x, q.y - zvv.y, q.z - zvv.z, q.w - zvv.w};
            ls += df.x * df.x + df.y * df.y + df.z * df.z + df.w * df.w;
            float4 o = {zvv.x + df.x, zvv.y + df.y, zvv.z + df.z, zvv.w + df.w};
            oz[(i >> 1) * 8 + quad * 2 + (i & 1)] = o;
        }
    }

#pragma unroll
    for (int off = 32; off > 0; off >>= 1) ls += __shfl_down(ls, off, 64);
    if (lane == 0) atomicAdd(loss_acc, ls);
}

// ---------------------------------------------------------------------------
__global__ void vq_scan(const int* __restrict__ cnt, int* __restrict__ cursor)
{
    __shared__ int tmp[K_CODES];
    int k = threadIdx.x;
    int c = cnt[k];
    tmp[k] = c;
    __syncthreads();
    for (int off = 1; off < K_CODES; off <<= 1) {
        int t = (k >= off) ? tmp[k - off] : 0;
        __syncthreads();
        tmp[k] += t;
        __syncthreads();
    }
    cursor[k] = tmp[k] - c;
}

__global__ void vq_scatter(const unsigned int* __restrict__ fidx,
                           int* __restrict__ cursor, unsigned int* __restrict__ bucket,
                           int* __restrict__ scode)
{
    int row = blockIdx.x * blockDim.x + threadIdx.x;
    int k = (int)fidx[row];
    int slot = atomicAdd(cursor + k, 1);
    bucket[slot] = (unsigned int)row;
    scode[slot]  = k;
}

// ---------------------------------------------------------------------------
// Skew-oblivious segment sum over code-sorted slots (R4-proven).
// ---------------------------------------------------------------------------
__global__ __launch_bounds__(128) void vq_segsum(
    const float* __restrict__ z, const unsigned int* __restrict__ bucket,
    const int* __restrict__ scode, float* __restrict__ be)
{
    __shared__ int sb[SEG_TILE];
    __shared__ int sc[SEG_TILE];
    const int tid = threadIdx.x;
    const int t0  = blockIdx.x * SEG_TILE;

    if (tid < SEG_TILE) sb[tid] = (int)bucket[t0 + tid];
    else if (tid < 2 * SEG_TILE) sc[tid - SEG_TILE] = scode[t0 + tid - SEG_TILE];
    __syncthreads();

    const int d = tid;
    float acc = 0.f;
    int cur = sc[0];

    for (int i = 0; i < SEG_TILE; i += 8) {
        float v[8];
#pragma unroll
        for (int j = 0; j < 8; ++j)
            v[j] = z[(size_t)sb[i + j] * D_DIM + d];
#pragma unroll
        for (int j = 0; j < 8; ++j) {
            int c = sc[i + j];
            if (c != cur) {
                atomicAdd(be + (size_t)cur * D_DIM + d, acc);
                acc = 0.f;
                cur = c;
            }
            acc += v[j];
        }
    }
    atomicAdd(be + (size_t)cur * D_DIM + d, acc);
}

// ---------------------------------------------------------------------------
__global__ void vq_finalize1(const float* __restrict__ cs, const int* __restrict__ cnt,
                             const float* __restrict__ loss_acc,
                             float* __restrict__ out_ncs, float* __restrict__ out_loss,
                             float* __restrict__ smoothed)
{
    __shared__ float red[K_CODES];
    int k = threadIdx.x;
    float ncs = cs[k] * DECAY_F + OMD_F * (float)cnt[k];
    out_ncs[k] = ncs;
    red[k] = ncs;
    __syncthreads();
    for (int s = 512; s > 0; s >>= 1) {
        if (k < s) red[k] += red[k + s];
        __syncthreads();
    }
    float n = red[0];
    smoothed[k] = (ncs + EPS_F) / (n + (float)K_CODES * EPS_F) * n;
    if (k == 0) out_loss[0] = loss_acc[0] / (float)((size_t)N_ROWS * D_DIM);
}

__global__ void vq_finalize2(const float* __restrict__ ema_w, const float* __restrict__ be,
                             const float* __restrict__ smoothed,
                             float* __restrict__ out_emb, float* __restrict__ out_ema)
{
    int i = blockIdx.x * blockDim.x + threadIdx.x;
    float e = ema_w[i] * DECAY_F + OMD_F * be[i];
    out_ema[i] = e;
    out_emb[i] = e / smoothed[i >> 7];
}

// ---------------------------------------------------------------------------
extern "C" void kernel_launch(void* const* d_in, const int* in_sizes, int n_in,
                              void* d_out, int out_size, void* d_ws, size_t ws_size,
                              hipStream_t stream) {
    const float* z   = (const float*)d_in[0];
    const float* emb = (const float*)d_in[1];
    const float* cs  = (const float*)d_in[2];
    const float* ema = (const float*)d_in[3];

    float* out    = (float*)d_out;
    float* o_zq   = out;
    float* o_idx  = o_zq + (size_t)N_ROWS * D_DIM;
    float* o_loss = o_idx + N_ROWS;
    float* o_emb  = o_loss + 1;
    float* o_ncs  = o_emb + K_CODES * D_DIM;
    float* o_ema  = o_ncs + K_CODES;

    float* ws = (float*)d_ws;
    int*            cnt      = (int*)(ws + WS_CNT);
    float*          lacc     = ws + WS_LOSS;
    float*          be       = ws + WS_BE;
    float*          enorm    = ws + WS_ENORM;
    float*          smoothed = ws + WS_SMOOTH;
    int*            cursor   = (int*)(ws + WS_CUR);
    unsigned int*   fidx     = (unsigned int*)(ws + WS_FIDX);
    unsigned int*   bucket   = (unsigned int*)(ws + WS_BUCKET);
    int*            scode    = (int*)(ws + WS_SCODE);
    unsigned short* eimg     = (unsigned short*)(ws + WS_EIMG);

    hipMemsetAsync(ws, 0, (size_t)WS_ZERO_END * sizeof(float), stream);
    vq_prep<<<128, 256, 0, stream>>>(emb, enorm, eimg);
    vq_score<<<256, 256, 0, stream>>>(z, eimg, enorm, emb,
                                      o_zq, o_idx, cnt, fidx, lacc);
    vq_scan<<<1, K_CODES, 0, stream>>>(cnt, cursor);
    vq_scatter<<<N_ROWS / 256, 256, 0, stream>>>(fidx, cursor, bucket, scode);
    vq_segsum<<<N_ROWS / SEG_TILE, 128, 0, stream>>>(z, bucket, scode, be);
    vq_finalize1<<<1, K_CODES, 0, stream>>>(cs, cnt, lacc, o_ncs, o_loss, smoothed);
    vq_finalize2<<<K_CODES * D_DIM / 256, 256, 0, stream>>>(ema, be, smoothed, o_emb, o_ema);
}